// Round 5
// baseline (4767.430 us; speedup 1.0000x reference)
//
#include <hip/hip_runtime.h>
#include <hip/hip_bf16.h>

// NGCF forward on MI355X — fully fused per-layer kernel, ws-size-robust.
//
// Algebra: x1 = e@W1.T is linear, so aggregation commutes with transform:
//   agg[i] = dsl[i]*(W1·S1[i]) + dis[i]*S2[i] ⊙ (W2·e[i])
//   S1[i]  = sum_{j in N(i)} dsl[j]*e[j] + dsl[i]*e[i]     (self loop folded)
//   S2[i]  = sum_{j in N(i)} dis[j]*e[j]
// => gather RAW embedding rows once per edge, transform per node in-register.
//
// Storage template: fp32 ping-pong (~279 MB ws) when it fits, bf16 storage
// (~166 MB ws, fp32 compute) as fallback. Branch on ws_size is call-invariant
// -> graph-capture safe.

#define SCAN_B 1024

__device__ __forceinline__ float ld_e(const float* p) { return *p; }
__device__ __forceinline__ float ld_e(const __hip_bfloat16* p) { return __bfloat162float(*p); }
__device__ __forceinline__ void st_e(float* p, float v) { *p = v; }
__device__ __forceinline__ void st_e(__hip_bfloat16* p, float v) { *p = __float2bfloat16(v); }

// 16B-per-lane row-slice load (fp32) / 8B (bf16), both fully coalesced per 16-lane group.
__device__ __forceinline__ float4 ld4(const float* p) {
  return *reinterpret_cast<const float4*>(p);
}
__device__ __forceinline__ float4 ld4(const __hip_bfloat16* p) {
  ushort4 u = *reinterpret_cast<const ushort4*>(p);
  float4 r;
  r.x = __uint_as_float((unsigned)u.x << 16);
  r.y = __uint_as_float((unsigned)u.y << 16);
  r.z = __uint_as_float((unsigned)u.z << 16);
  r.w = __uint_as_float((unsigned)u.w << 16);
  return r;
}

__global__ void zero_i32(int* __restrict__ p, int n) {
  int i = blockIdx.x * blockDim.x + threadIdx.x;
  if (i < n) p[i] = 0;
}

__global__ void count_deg(const int* __restrict__ users, const int* __restrict__ pos,
                          int* __restrict__ deg, int b) {
  int i = blockIdx.x * blockDim.x + threadIdx.x;
  if (i < b) {
    atomicAdd(&deg[users[i]], 1);
    atomicAdd(&deg[pos[i]], 1);
  }
}

__global__ void scan1(const int* __restrict__ deg, int* __restrict__ tmp,
                      int* __restrict__ partial, int n) {
  __shared__ int sh[SCAN_B];
  int tid = threadIdx.x;
  int i = blockIdx.x * SCAN_B + tid;
  sh[tid] = (i < n) ? deg[i] : 0;
  __syncthreads();
  for (int off = 1; off < SCAN_B; off <<= 1) {
    int t = (tid >= off) ? sh[tid - off] : 0;
    __syncthreads();
    sh[tid] += t;
    __syncthreads();
  }
  if (i < n) tmp[i] = sh[tid];
  if (tid == SCAN_B - 1) partial[blockIdx.x] = sh[tid];
}

__global__ void scan2(int* __restrict__ partial, int g) {
  __shared__ int sh[SCAN_B];
  int tid = threadIdx.x;
  sh[tid] = (tid < g) ? partial[tid] : 0;
  __syncthreads();
  for (int off = 1; off < SCAN_B; off <<= 1) {
    int t = (tid >= off) ? sh[tid - off] : 0;
    __syncthreads();
    sh[tid] += t;
    __syncthreads();
  }
  if (tid < g) partial[tid] = sh[tid];
}

__global__ void scan3(const int* __restrict__ tmp, const int* __restrict__ partial,
                      const int* __restrict__ deg, int* __restrict__ rowptr,
                      int* __restrict__ cursor, int n) {
  int i = blockIdx.x * blockDim.x + threadIdx.x;
  if (i < n) {
    int blk = i >> 10;                       // SCAN_B == 1024
    int off = blk > 0 ? partial[blk - 1] : 0;
    int incl = tmp[i] + off;
    rowptr[i + 1] = incl;
    cursor[i] = incl - deg[i];               // exclusive prefix = list start
    if (i == 0) rowptr[0] = 0;
  }
}

// dd[i] = (dis_i, dsl_i)
__global__ void compute_dd(const int* __restrict__ deg, float2* __restrict__ dd, int n) {
  int i = blockIdx.x * blockDim.x + threadIdx.x;
  if (i < n) {
    float d = (float)deg[i];
    float dis = deg[i] > 0 ? 1.0f / sqrtf(d) : 0.0f;
    float dsl = 1.0f / sqrtf(d + 1.0f);
    dd[i] = make_float2(dis, dsl);
  }
}

__global__ void fill_adj(const int* __restrict__ users, const int* __restrict__ pos,
                         int* __restrict__ cursor, int* __restrict__ adj, int b) {
  int i = blockIdx.x * blockDim.x + threadIdx.x;
  if (i < b) {
    int u = users[i], p = pos[i];
    adj[atomicAdd(&cursor[p], 1)] = u;   // edge u -> p lands in p's in-list
    adj[atomicAdd(&cursor[u], 1)] = p;   // edge p -> u lands in u's in-list
  }
}

// One fused NGCF layer. One wave per node, lane = dim.
//   gather raw rows -> S1,S2 in regs -> W1·S1, W2·e via LDS+shfl matvec
//   -> leaky_relu -> row L2 norm -> e_out.
template <typename SIN, typename SOUT>
__global__ void layer_fused(const SIN* __restrict__ e_in, const float* __restrict__ W1,
                            const float* __restrict__ W2, const int* __restrict__ rowptr,
                            const int* __restrict__ adj, const float2* __restrict__ dd,
                            SOUT* __restrict__ e_out, int n) {
  __shared__ float w1s[64][65];   // +1 pad: lane d, iter k -> bank (d+k)%32, 2-way (free)
  __shared__ float w2s[64][65];
  int tid = threadIdx.x;
  for (int i = tid; i < 4096; i += 512) {
    int r = i >> 6, c = i & 63;
    w1s[r][c] = W1[i];
    w2s[r][c] = W2[i];
  }
  __syncthreads();
  int lane = tid & 63;
  int wid = blockIdx.x * (blockDim.x >> 6) + (tid >> 6);
  if (wid >= n) return;
  int rs = rowptr[wid], re = rowptr[wid + 1];
  float2 dd_i = dd[wid];
  float di = dd_i.x, dsl_i = dd_i.y;
  size_t base = (size_t)wid * 64 + lane;
  float ev = ld_e(&e_in[base]);
  float s1 = dsl_i * ev;          // self-loop term
  float s2 = 0.0f;
  for (int cs = rs; cs < re; cs += 64) {
    int cnt = min(64, re - cs);
    int jv = 0;
    float dv = 0.0f, lv = 0.0f;
    if (cs + lane < re) {         // coalesced id stage + dd stage (once per 64 edges)
      jv = adj[cs + lane];
      float2 t = dd[jv];
      dv = t.x; lv = t.y;
    }
    int k = 0;
    for (; k + 3 < cnt; k += 4) {  // 4 row-gathers in flight
      int j0 = __shfl(jv, k), j1 = __shfl(jv, k + 1);
      int j2 = __shfl(jv, k + 2), j3 = __shfl(jv, k + 3);
      float l0 = __shfl(lv, k), l1 = __shfl(lv, k + 1);
      float l2 = __shfl(lv, k + 2), l3 = __shfl(lv, k + 3);
      float d0 = __shfl(dv, k), d1 = __shfl(dv, k + 1);
      float d2 = __shfl(dv, k + 2), d3 = __shfl(dv, k + 3);
      float v0 = ld_e(&e_in[(size_t)j0 * 64 + lane]);
      float v1 = ld_e(&e_in[(size_t)j1 * 64 + lane]);
      float v2 = ld_e(&e_in[(size_t)j2 * 64 + lane]);
      float v3 = ld_e(&e_in[(size_t)j3 * 64 + lane]);
      s1 = fmaf(l0, v0, s1); s2 = fmaf(d0, v0, s2);
      s1 = fmaf(l1, v1, s1); s2 = fmaf(d1, v1, s2);
      s1 = fmaf(l2, v2, s1); s2 = fmaf(d2, v2, s2);
      s1 = fmaf(l3, v3, s1); s2 = fmaf(d3, v3, s2);
    }
    for (; k < cnt; ++k) {
      int j = __shfl(jv, k);
      float lk = __shfl(lv, k), dk = __shfl(dv, k);
      float v = ld_e(&e_in[(size_t)j * 64 + lane]);
      s1 = fmaf(lk, v, s1); s2 = fmaf(dk, v, s2);
    }
  }
  // t1 = W1·S1, t2 = W2·e_i  (lane d owns output dim d; shfl broadcast)
  float t1 = 0.0f, t2 = 0.0f;
#pragma unroll
  for (int k = 0; k < 64; ++k) {
    float s1k = __shfl(s1, k);
    float evk = __shfl(ev, k);
    t1 = fmaf(w1s[lane][k], s1k, t1);
    t2 = fmaf(w2s[lane][k], evk, t2);
  }
  float agg = fmaf(dsl_i, t1, di * s2 * t2);
  float v = agg >= 0.0f ? agg : 0.2f * agg;   // leaky_relu(0.2)
  float s = v * v;
#pragma unroll
  for (int m = 32; m; m >>= 1) s += __shfl_xor(s, m);
  float inv = 1.0f / fmaxf(sqrtf(s), 1e-12f);
  st_e(&e_out[base], v * inv);
}

// sims += dot(e[u],e[p]), dot(e[u],e[g]) over this layer's 64-dim slice.
// 16-lane group per interaction, float4 row slices (256B coalesced per group),
// 4-step intra-group reduction. 4 interactions per wave.
template <typename ST>
__global__ void simk(const ST* __restrict__ ef, const int* __restrict__ users,
                     const int* __restrict__ pos, const int* __restrict__ neg,
                     float* __restrict__ out, int btot, int first) {
  int tid = blockIdx.x * blockDim.x + threadIdx.x;
  int q = tid & 15;        // lane within group
  int b = tid >> 4;        // interaction id (uniform within group)
  if (b >= btot) return;
  int u = users[b], p = pos[b], g = neg[b];   // same addr across group -> broadcast
  float4 eu = ld4(&ef[(size_t)u * 64 + q * 4]);
  float4 ep = ld4(&ef[(size_t)p * 64 + q * 4]);
  float4 eg = ld4(&ef[(size_t)g * 64 + q * 4]);
  float dp = eu.x * ep.x + eu.y * ep.y + eu.z * ep.z + eu.w * ep.w;
  float dn = eu.x * eg.x + eu.y * eg.y + eu.z * eg.z + eu.w * eg.w;
#pragma unroll
  for (int m = 8; m; m >>= 1) {    // stays within the 16-lane group
    dp += __shfl_xor(dp, m);
    dn += __shfl_xor(dn, m);
  }
  if (q == 0) {
    if (first) {
      out[b] = dp;
      out[btot + b] = dn;
    } else {
      out[b] += dp;
      out[btot + b] += dn;
    }
  }
}

template <typename ST>
static void run_pipeline(const float* E, const float* W1a, const float* W2a,
                         const float* W1b, const float* W2b, const float* W1c,
                         const float* W2c, const int* users, const int* pos,
                         const int* neg, float* out, void* d_ws, int N, int B,
                         hipStream_t stream) {
  // Workspace: rowptr, adj, dd persistent; eb0/eb1 ping-pong (type ST).
  // CSR temporaries (deg/tmp/cursor/partial, ~8 MB) OVERLAP eb1 — dead before
  // eb1's first write (layer 2's output).
  size_t off = 0;
  auto alloc = [&](size_t bytes) -> void* {
    void* p = (char*)d_ws + off;
    off += (bytes + 255) & ~(size_t)255;
    return p;
  };
  int*    rowptr = (int*)alloc((size_t)(N + 1) * 4);
  int*    adj    = (int*)alloc((size_t)(2 * B) * 4);
  float2* dd     = (float2*)alloc((size_t)N * 8);
  ST*     eb0    = (ST*)alloc((size_t)N * 64 * sizeof(ST));
  ST*     eb1    = (ST*)alloc((size_t)N * 64 * sizeof(ST));
  char* tbase  = (char*)eb1;
  int* deg     = (int*)tbase;
  int* tmp     = (int*)(tbase + (size_t)N * 4);
  int* cursor  = (int*)(tbase + (size_t)N * 8);
  int* partial = (int*)(tbase + (size_t)N * 12);

  int gN = (N + 255) / 256;
  int gB = (B + 255) / 256;
  int G1 = (N + SCAN_B - 1) / SCAN_B;

  zero_i32<<<gN, 256, 0, stream>>>(deg, N);
  count_deg<<<gB, 256, 0, stream>>>(users, pos, deg, B);
  scan1<<<G1, SCAN_B, 0, stream>>>(deg, tmp, partial, N);
  scan2<<<1, SCAN_B, 0, stream>>>(partial, G1);
  scan3<<<gN, 256, 0, stream>>>(tmp, partial, deg, rowptr, cursor, N);
  compute_dd<<<gN, 256, 0, stream>>>(deg, dd, N);
  fill_adj<<<gB, 256, 0, stream>>>(users, pos, cursor, adj, B);

  int gw  = (N + 7) / 8;                              // 8 waves / 512-thread block
  int gs  = (int)(((size_t)B * 16 + 255) / 256);      // 16 lanes per interaction

  simk<float><<<gs, 256, 0, stream>>>(E, users, pos, neg, out, B, 1);

  layer_fused<float, ST><<<gw, 512, 0, stream>>>(E, W1a, W2a, rowptr, adj, dd, eb0, N);
  simk<ST><<<gs, 256, 0, stream>>>(eb0, users, pos, neg, out, B, 0);

  layer_fused<ST, ST><<<gw, 512, 0, stream>>>(eb0, W1b, W2b, rowptr, adj, dd, eb1, N);
  simk<ST><<<gs, 256, 0, stream>>>(eb1, users, pos, neg, out, B, 0);

  layer_fused<ST, ST><<<gw, 512, 0, stream>>>(eb1, W1c, W2c, rowptr, adj, dd, eb0, N);
  simk<ST><<<gs, 256, 0, stream>>>(eb0, users, pos, neg, out, B, 0);
}

extern "C" void kernel_launch(void* const* d_in, const int* in_sizes, int n_in,
                              void* d_out, int out_size, void* d_ws, size_t ws_size,
                              hipStream_t stream) {
  const float* E   = (const float*)d_in[0];
  const float* W1a = (const float*)d_in[1];
  const float* W2a = (const float*)d_in[2];
  const float* W1b = (const float*)d_in[3];
  const float* W2b = (const float*)d_in[4];
  const float* W1c = (const float*)d_in[5];
  const float* W2c = (const float*)d_in[6];
  const int* users = (const int*)d_in[7];
  const int* pos   = (const int*)d_in[8];
  const int* neg   = (const int*)d_in[9];
  const int N = in_sizes[0] / 64;
  const int B = in_sizes[7];
  float* out = (float*)d_out;

  // Required ws: fixed part (rowptr+adj+dd, 256B-aligned each) + 2 emb buffers.
  size_t fixed = (((size_t)(N + 1) * 4 + 255) & ~(size_t)255) +
                 (((size_t)(2 * B) * 4 + 255) & ~(size_t)255) +
                 (((size_t)N * 8 + 255) & ~(size_t)255);
  size_t need_f32 = fixed + 2 * ((((size_t)N * 64 * 4) + 255) & ~(size_t)255);

  if (ws_size >= need_f32) {
    run_pipeline<float>(E, W1a, W2a, W1b, W2b, W1c, W2c, users, pos, neg,
                        out, d_ws, N, B, stream);
  } else {
    run_pipeline<__hip_bfloat16>(E, W1a, W2a, W1b, W2b, W1c, W2c, users, pos,
                                 neg, out, d_ws, N, B, stream);
  }
}

// Round 8
// 2874.078 us; speedup vs baseline: 1.6588x; 1.6588x over previous
//
#include <hip/hip_runtime.h>
#include <hip/hip_bf16.h>

// NGCF forward on MI355X — fused per-layer kernel, scalar-pipe edge loop,
// fully predicated batch-of-8 gathers (no serial tail).
//
// Algebra: x1 = e@W1.T is linear, so aggregation commutes with transform:
//   agg[i] = dsl[i]*(W1·S1[i]) + dis[i]*S2[i] ⊙ (W2·e[i])
//   S1[i]  = sum_{j in N(i)} dsl[j]*e[j] + dsl[i]*e[i]
//   S2[i]  = sum_{j in N(i)} dis[j]*e[j]
//
// R5 counters: layer_fused 1166us @ 694GB/s (8.7% peak), VALUBusy 30%,
// WRITE_SIZE=128MB -> fp32 path ran (ws >= 278MB); FETCH 664MB vs 1GB gather
// volume -> gathers mostly reach HBM; 105us BW floor vs 1166us measured ->
// latency-bound. Fix (R6+R7): readfirstlane(wid) -> s_load for rowptr/adj/dd
// (scalar pipe, no bpermute), predicated batches of 8 independent gathers for
// ALL nodes (items avg deg~5 otherwise serialize), W in LDS chunk-major
// float4 (ds_read_b128 conflict-free), explicit v_readlane broadcasts.

#define SCAN_B 1024

__device__ __forceinline__ float ld_e(const float* p) { return *p; }
__device__ __forceinline__ float ld_e(const __hip_bfloat16* p) { return __bfloat162float(*p); }
__device__ __forceinline__ void st_e(float* p, float v) { *p = v; }
__device__ __forceinline__ void st_e(__hip_bfloat16* p, float v) { *p = __float2bfloat16(v); }

__device__ __forceinline__ float bcastf(float x, int k) {
  return __uint_as_float((unsigned)__builtin_amdgcn_readlane(__float_as_uint(x), k));
}

// 16B/8B-per-lane row-slice loads for simk (coalesced per 16-lane group).
__device__ __forceinline__ float4 ld4(const float* p) {
  return *reinterpret_cast<const float4*>(p);
}
__device__ __forceinline__ float4 ld4(const __hip_bfloat16* p) {
  ushort4 u = *reinterpret_cast<const ushort4*>(p);
  float4 r;
  r.x = __uint_as_float((unsigned)u.x << 16);
  r.y = __uint_as_float((unsigned)u.y << 16);
  r.z = __uint_as_float((unsigned)u.z << 16);
  r.w = __uint_as_float((unsigned)u.w << 16);
  return r;
}

__global__ void zero_i32(int* __restrict__ p, int n) {
  int i = blockIdx.x * blockDim.x + threadIdx.x;
  if (i < n) p[i] = 0;
}

__global__ void count_deg(const int* __restrict__ users, const int* __restrict__ pos,
                          int* __restrict__ deg, int b) {
  int i = blockIdx.x * blockDim.x + threadIdx.x;
  if (i < b) {
    atomicAdd(&deg[users[i]], 1);
    atomicAdd(&deg[pos[i]], 1);
  }
}

__global__ void scan1(const int* __restrict__ deg, int* __restrict__ tmp,
                      int* __restrict__ partial, int n) {
  __shared__ int sh[SCAN_B];
  int tid = threadIdx.x;
  int i = blockIdx.x * SCAN_B + tid;
  sh[tid] = (i < n) ? deg[i] : 0;
  __syncthreads();
  for (int off = 1; off < SCAN_B; off <<= 1) {
    int t = (tid >= off) ? sh[tid - off] : 0;
    __syncthreads();
    sh[tid] += t;
    __syncthreads();
  }
  if (i < n) tmp[i] = sh[tid];
  if (tid == SCAN_B - 1) partial[blockIdx.x] = sh[tid];
}

__global__ void scan2(int* __restrict__ partial, int g) {
  __shared__ int sh[SCAN_B];
  int tid = threadIdx.x;
  sh[tid] = (tid < g) ? partial[tid] : 0;
  __syncthreads();
  for (int off = 1; off < SCAN_B; off <<= 1) {
    int t = (tid >= off) ? sh[tid - off] : 0;
    __syncthreads();
    sh[tid] += t;
    __syncthreads();
  }
  if (tid < g) partial[tid] = sh[tid];
}

__global__ void scan3(const int* __restrict__ tmp, const int* __restrict__ partial,
                      const int* __restrict__ deg, int* __restrict__ rowptr,
                      int* __restrict__ cursor, int n) {
  int i = blockIdx.x * blockDim.x + threadIdx.x;
  if (i < n) {
    int blk = i >> 10;                       // SCAN_B == 1024
    int off = blk > 0 ? partial[blk - 1] : 0;
    int incl = tmp[i] + off;
    rowptr[i + 1] = incl;
    cursor[i] = incl - deg[i];               // exclusive prefix = list start
    if (i == 0) rowptr[0] = 0;
  }
}

// dd[i] = (dis_i, dsl_i)
__global__ void compute_dd(const int* __restrict__ deg, float2* __restrict__ dd, int n) {
  int i = blockIdx.x * blockDim.x + threadIdx.x;
  if (i < n) {
    float d = (float)deg[i];
    float dis = deg[i] > 0 ? 1.0f / sqrtf(d) : 0.0f;
    float dsl = 1.0f / sqrtf(d + 1.0f);
    dd[i] = make_float2(dis, dsl);
  }
}

__global__ void fill_adj(const int* __restrict__ users, const int* __restrict__ pos,
                         int* __restrict__ cursor, int* __restrict__ adj, int b) {
  int i = blockIdx.x * blockDim.x + threadIdx.x;
  if (i < b) {
    int u = users[i], p = pos[i];
    adj[atomicAdd(&cursor[p], 1)] = u;   // edge u -> p lands in p's in-list
    adj[atomicAdd(&cursor[u], 1)] = p;   // edge p -> u lands in u's in-list
  }
}

// One fused NGCF layer. One wave per node, lane = dim.
template <typename SIN, typename SOUT>
__global__ void layer_fused(const SIN* __restrict__ e_in, const float* __restrict__ W1,
                            const float* __restrict__ W2, const int* __restrict__ rowptr,
                            const int* __restrict__ adj, const float2* __restrict__ dd,
                            SOUT* __restrict__ e_out, int n) {
  // chunk-major float4: w1f4[m*64+d] = W1[d][4m..4m+3]  (lane reads own slot ->
  // consecutive lanes consecutive 16B slots -> conflict-free ds_read_b128)
  __shared__ float4 w1f4[1024];
  __shared__ float4 w2f4[1024];
  int tid = threadIdx.x;
  for (int i = tid; i < 1024; i += 512) {
    int m = i >> 6, d = i & 63;
    w1f4[i] = *reinterpret_cast<const float4*>(&W1[d * 64 + 4 * m]);
    w2f4[i] = *reinterpret_cast<const float4*>(&W2[d * 64 + 4 * m]);
  }
  __syncthreads();
  int lane = tid & 63;
  int wid = blockIdx.x * (blockDim.x >> 6) + (tid >> 6);
  if (wid >= n) return;
  int wu = __builtin_amdgcn_readfirstlane(wid);   // SGPR -> scalar loads below
  int rs = rowptr[wu], re = rowptr[wu + 1];       // s_load
  float2 dd_i = dd[wu];                           // s_load_dwordx2
  float di = dd_i.x, dsl_i = dd_i.y;
  size_t base = (size_t)wu * 64 + lane;
  float ev = ld_e(&e_in[base]);
  float s1 = dsl_i * ev;          // self-loop term
  float s2 = 0.0f;
  // Predicated batches of 8: every slot issues an independent load; padding
  // slots (q >= m) clamp to adj[rs] (same line as a real gather -> cached)
  // and get zero weights. No serial tail, no divergence (m is wave-uniform).
  for (int e = rs; e < re; e += 8) {
    int m = re - e;                 // >= 1 inside loop
    int j[8];
    float2 w[8];
    float v[8];
#pragma unroll
    for (int q = 0; q < 8; ++q) {
      int idx = (q < m) ? (e + q) : rs;
      j[q] = adj[idx];              // uniform addr -> s_load, 8 in flight
    }
#pragma unroll
    for (int q = 0; q < 8; ++q) w[q] = dd[j[q]];   // uniform -> s_load, L2-resident
#pragma unroll
    for (int q = 0; q < 8; ++q) v[q] = ld_e(&e_in[(size_t)j[q] * 64 + lane]);
#pragma unroll
    for (int q = 0; q < 8; ++q) {
      float ly = (q < m) ? w[q].y : 0.0f;
      float lx = (q < m) ? w[q].x : 0.0f;
      s1 = fmaf(ly, v[q], s1);
      s2 = fmaf(lx, v[q], s2);
    }
  }
  // t1 = W1·S1, t2 = W2·e_i ; lane d owns output dim d, v_readlane broadcasts.
  float t1 = 0.0f, t2 = 0.0f;
#pragma unroll
  for (int m = 0; m < 16; ++m) {
    float4 wa = w1f4[(m << 6) | lane];
    float4 wb = w2f4[(m << 6) | lane];
    int k = m << 2;
    t1 = fmaf(wa.x, bcastf(s1, k), t1);
    t2 = fmaf(wb.x, bcastf(ev, k), t2);
    t1 = fmaf(wa.y, bcastf(s1, k + 1), t1);
    t2 = fmaf(wb.y, bcastf(ev, k + 1), t2);
    t1 = fmaf(wa.z, bcastf(s1, k + 2), t1);
    t2 = fmaf(wb.z, bcastf(ev, k + 2), t2);
    t1 = fmaf(wa.w, bcastf(s1, k + 3), t1);
    t2 = fmaf(wb.w, bcastf(ev, k + 3), t2);
  }
  float agg = fmaf(dsl_i, t1, di * s2 * t2);
  float v = agg >= 0.0f ? agg : 0.2f * agg;   // leaky_relu(0.2)
  float s = v * v;
#pragma unroll
  for (int m = 32; m; m >>= 1) s += __shfl_xor(s, m);
  float inv = 1.0f / fmaxf(sqrtf(s), 1e-12f);
  st_e(&e_out[base], v * inv);
}

// sims += dot(e[u],e[p]), dot(e[u],e[g]) over this layer's 64-dim slice.
// 16-lane group per interaction, float4/ushort4 row slices.
template <typename ST>
__global__ void simk(const ST* __restrict__ ef, const int* __restrict__ users,
                     const int* __restrict__ pos, const int* __restrict__ neg,
                     float* __restrict__ out, int btot, int first) {
  int tid = blockIdx.x * blockDim.x + threadIdx.x;
  int q = tid & 15;        // lane within group
  int b = tid >> 4;        // interaction id (uniform within group)
  if (b >= btot) return;
  int u = users[b], p = pos[b], g = neg[b];
  float4 eu = ld4(&ef[(size_t)u * 64 + q * 4]);
  float4 ep = ld4(&ef[(size_t)p * 64 + q * 4]);
  float4 eg = ld4(&ef[(size_t)g * 64 + q * 4]);
  float dp = eu.x * ep.x + eu.y * ep.y + eu.z * ep.z + eu.w * ep.w;
  float dn = eu.x * eg.x + eu.y * eg.y + eu.z * eg.z + eu.w * eg.w;
#pragma unroll
  for (int m = 8; m; m >>= 1) {    // stays within the 16-lane group
    dp += __shfl_xor(dp, m);
    dn += __shfl_xor(dn, m);
  }
  if (q == 0) {
    if (first) {
      out[b] = dp;
      out[btot + b] = dn;
    } else {
      out[b] += dp;
      out[btot + b] += dn;
    }
  }
}

template <typename ST>
static void run_pipeline(const float* E, const float* W1a, const float* W2a,
                         const float* W1b, const float* W2b, const float* W1c,
                         const float* W2c, const int* users, const int* pos,
                         const int* neg, float* out, void* d_ws, int N, int B,
                         hipStream_t stream) {
  // Workspace: rowptr, adj, dd persistent; eb0/eb1 ping-pong (type ST).
  // CSR temporaries (deg/tmp/cursor/partial, ~8 MB) OVERLAP eb1 — dead before
  // eb1's first write (layer 2's output).
  size_t off = 0;
  auto alloc = [&](size_t bytes) -> void* {
    void* p = (char*)d_ws + off;
    off += (bytes + 255) & ~(size_t)255;
    return p;
  };
  int*    rowptr = (int*)alloc((size_t)(N + 1) * 4);
  int*    adj    = (int*)alloc((size_t)(2 * B) * 4);
  float2* dd     = (float2*)alloc((size_t)N * 8);
  ST*     eb0    = (ST*)alloc((size_t)N * 64 * sizeof(ST));
  ST*     eb1    = (ST*)alloc((size_t)N * 64 * sizeof(ST));
  char* tbase  = (char*)eb1;
  int* deg     = (int*)tbase;
  int* tmp     = (int*)(tbase + (size_t)N * 4);
  int* cursor  = (int*)(tbase + (size_t)N * 8);
  int* partial = (int*)(tbase + (size_t)N * 12);

  int gN = (N + 255) / 256;
  int gB = (B + 255) / 256;
  int G1 = (N + SCAN_B - 1) / SCAN_B;

  zero_i32<<<gN, 256, 0, stream>>>(deg, N);
  count_deg<<<gB, 256, 0, stream>>>(users, pos, deg, B);
  scan1<<<G1, SCAN_B, 0, stream>>>(deg, tmp, partial, N);
  scan2<<<1, SCAN_B, 0, stream>>>(partial, G1);
  scan3<<<gN, 256, 0, stream>>>(tmp, partial, deg, rowptr, cursor, N);
  compute_dd<<<gN, 256, 0, stream>>>(deg, dd, N);
  fill_adj<<<gB, 256, 0, stream>>>(users, pos, cursor, adj, B);

  int gw  = (N + 7) / 8;                              // 8 waves / 512-thread block
  int gs  = (int)(((size_t)B * 16 + 255) / 256);      // 16 lanes per interaction

  simk<float><<<gs, 256, 0, stream>>>(E, users, pos, neg, out, B, 1);

  layer_fused<float, ST><<<gw, 512, 0, stream>>>(E, W1a, W2a, rowptr, adj, dd, eb0, N);
  simk<ST><<<gs, 256, 0, stream>>>(eb0, users, pos, neg, out, B, 0);

  layer_fused<ST, ST><<<gw, 512, 0, stream>>>(eb0, W1b, W2b, rowptr, adj, dd, eb1, N);
  simk<ST><<<gs, 256, 0, stream>>>(eb1, users, pos, neg, out, B, 0);

  layer_fused<ST, ST><<<gw, 512, 0, stream>>>(eb1, W1c, W2c, rowptr, adj, dd, eb0, N);
  simk<ST><<<gs, 256, 0, stream>>>(eb0, users, pos, neg, out, B, 0);
}

extern "C" void kernel_launch(void* const* d_in, const int* in_sizes, int n_in,
                              void* d_out, int out_size, void* d_ws, size_t ws_size,
                              hipStream_t stream) {
  const float* E   = (const float*)d_in[0];
  const float* W1a = (const float*)d_in[1];
  const float* W2a = (const float*)d_in[2];
  const float* W1b = (const float*)d_in[3];
  const float* W2b = (const float*)d_in[4];
  const float* W1c = (const float*)d_in[5];
  const float* W2c = (const float*)d_in[6];
  const int* users = (const int*)d_in[7];
  const int* pos   = (const int*)d_in[8];
  const int* neg   = (const int*)d_in[9];
  const int N = in_sizes[0] / 64;
  const int B = in_sizes[7];
  float* out = (float*)d_out;

  // Required ws: fixed part (rowptr+adj+dd, 256B-aligned each) + 2 emb buffers.
  size_t fixed = (((size_t)(N + 1) * 4 + 255) & ~(size_t)255) +
                 (((size_t)(2 * B) * 4 + 255) & ~(size_t)255) +
                 (((size_t)N * 8 + 255) & ~(size_t)255);
  size_t need_f32 = fixed + 2 * ((((size_t)N * 64 * 4) + 255) & ~(size_t)255);

  if (ws_size >= need_f32) {
    run_pipeline<float>(E, W1a, W2a, W1b, W2b, W1c, W2c, users, pos, neg,
                        out, d_ws, N, B, stream);
  } else {
    run_pipeline<__hip_bfloat16>(E, W1a, W2a, W1b, W2b, W1c, W2c, users, pos,
                                 neg, out, d_ws, N, B, stream);
  }
}